// Round 1
// 951.614 us; speedup vs baseline: 1.1543x; 1.1543x over previous
//
#include <hip/hip_runtime.h>
#include <hip/hip_bf16.h>

#define U_CNT 200000
#define I_CNT 100000
#define N_CNT 300000
#define E_CNT 1000000
#define ATTR_D 8
#define H_DIM 32
#define NB_SCAN ((N_CNT + 255) / 256)

// NOTE (rounds 1-4): all float inputs and the output are FLOAT32. absmax floor
// 1.95e-3 == bf16 rounding of the *reference*; threshold 1.26e-2.
// NOTE (round 5): k_edge_mlp was atomic-bound (4M atomics x 32B = 128MB WRITE).
// NOTE (round 6): deg via segment-sum post-scatter; dis[row] folded by k_rescale.
// NOTE (round 7, this round): k_scatter was scattered-REQUEST bound (4M random
// ops: 2M 8B stores + 2M cursor atomics; HBM only 10% of peak). (a) ranks are
// captured from k_edge_mlp's existing cnt atomics -> scatter position is
// offs[node]+rank, cursor atomics gone. (b) y-space reformulation
// (y = dis*x; y' = dis^2*(sum w*y[row] + y[c]); l2norm is scale-invariant)
// eliminates k_rescale entirely; CSR keeps raw w.

// ---------------- edge MLP + count histogram; rank capture ----------------
__global__ void k_edge_mlp(const int* __restrict__ src, const int* __restrict__ dst,
                           const float* __restrict__ attr,
                           const float* __restrict__ W1, const float* __restrict__ b1,
                           const float* __restrict__ W2, const float* __restrict__ b2,
                           int2* __restrict__ wr, int* __restrict__ cnt) {
    __shared__ float sW1[ATTR_D * H_DIM];
    __shared__ float sb1[H_DIM];
    __shared__ float sW2[H_DIM];
    __shared__ float sb2;
    int t = threadIdx.x;
    sW1[t] = W1[t];                      // blockDim==256==ATTR_D*H_DIM
    if (t < H_DIM) { sb1[t] = b1[t]; sW2[t] = W2[t]; }
    if (t == 0) sb2 = b2[0];
    __syncthreads();
    int e = blockIdx.x * 256 + t;
    if (e >= E_CNT) return;
    const float4* a4 = (const float4*)attr;     // 32B/row: two float4
    float4 r0 = a4[e * 2 + 0];
    float4 r1 = a4[e * 2 + 1];
    float a[8] = {r0.x, r0.y, r0.z, r0.w, r1.x, r1.y, r1.z, r1.w};
    float z = sb2;
    #pragma unroll
    for (int h = 0; h < H_DIM; ++h) {
        float acc = sb1[h];
        #pragma unroll
        for (int k = 0; k < 8; ++k) acc = fmaf(a[k], sW1[k * H_DIM + h], acc);
        acc = fmaxf(acc, 0.0f);
        z = fmaf(acc, sW2[h], z);
    }
    float w = 1.0f / (1.0f + __expf(-z));
    w = fmaxf(w, 1e-6f);
    int s = src[e], d = U_CNT + dst[e];
    int rs = atomicAdd(&cnt[s], 1);      // rank of e within node s's list
    int rd = atomicAdd(&cnt[d], 1);      // rank of e within node d's list
    wr[e] = make_int2(__float_as_int(w), rs | (rd << 16));   // deg << 65536
}

// ---------------- exclusive scan of cnt -> offs (3 kernels) ----------------
__global__ void k_scan1(const int* __restrict__ cnt, int* __restrict__ incl,
                        int* __restrict__ bsums) {
    __shared__ int s[256];
    int t = threadIdx.x;
    int i = blockIdx.x * 256 + t;
    int v = (i < N_CNT) ? cnt[i] : 0;
    s[t] = v;
    __syncthreads();
    #pragma unroll
    for (int off = 1; off < 256; off <<= 1) {
        int x = (t >= off) ? s[t - off] : 0;
        __syncthreads();
        s[t] += x;
        __syncthreads();
    }
    if (i < N_CNT) incl[i] = s[t];
    if (t == 255) bsums[blockIdx.x] = s[255];
}

__global__ void k_scan2(const int* __restrict__ bsums, int* __restrict__ bbase, int nb) {
    __shared__ int s[256];
    __shared__ int carry_s;
    int t = threadIdx.x;
    if (t == 0) carry_s = 0;
    __syncthreads();
    for (int start = 0; start < nb; start += 256) {
        int i = start + t;
        int v = (i < nb) ? bsums[i] : 0;
        s[t] = v;
        __syncthreads();
        #pragma unroll
        for (int off = 1; off < 256; off <<= 1) {
            int x = (t >= off) ? s[t - off] : 0;
            __syncthreads();
            s[t] += x;
            __syncthreads();
        }
        int carry = carry_s;
        if (i < nb) bbase[i] = carry + s[t] - v;  // exclusive
        __syncthreads();
        if (t == 255) carry_s += s[255];
        __syncthreads();
    }
}

__global__ void k_scan3(const int* __restrict__ incl, const int* __restrict__ cnt,
                        const int* __restrict__ bbase, int* __restrict__ offs) {
    int i = blockIdx.x * 256 + threadIdx.x;
    if (i < N_CNT) offs[i] = bbase[blockIdx.x] + incl[i] - cnt[i];
    if (i == 0) offs[N_CNT] = 2 * E_CNT;
}

// ---------------- scatter edges into CSR at offs[node]+rank (no atomics) ----------------
__global__ void k_scatter(const int* __restrict__ src, const int* __restrict__ dst,
                          const int2* __restrict__ wr, const int* __restrict__ offs,
                          int2* __restrict__ csr) {
    int e = blockIdx.x * 256 + threadIdx.x;
    if (e >= E_CNT) return;
    int2 v = wr[e];
    unsigned rk = (unsigned)v.y;
    int s = src[e], d = U_CNT + dst[e];
    csr[offs[s] + (rk & 0xffffu)] = make_int2(d, v.x);   // row under s, partner d
    csr[offs[d] + (rk >> 16)]     = make_int2(s, v.x);   // row under d, partner s
}

// ---------------- deg via segment sum (no atomics), dis = rsqrt(1+sum) ----------------
__global__ void k_deg(const int* __restrict__ offs, const int2* __restrict__ csr,
                      float* __restrict__ dis) {
    int i = blockIdx.x * 256 + threadIdx.x;
    if (i >= N_CNT) return;
    int b = offs[i], e = offs[i + 1];
    float s = 1.0f;                      // self loop weight
    for (int k = b; k < e; ++k) s += __int_as_float(csr[k].y);
    dis[i] = rsqrtf(s);                  // s >= 1 always
}

// ---------------- initial features: users y0 = dis * l2norm(user_w) ----------------
__global__ void k_users(const float* __restrict__ user_w, const float* __restrict__ dis,
                        float* __restrict__ y0, float* __restrict__ acc, int use_acc) {
    int lane = threadIdx.x & 63;
    int wv = (blockIdx.x * blockDim.x + threadIdx.x) >> 6;
    int nw = (gridDim.x * blockDim.x) >> 6;
    for (int r = wv; r < U_CNT; r += nw) {
        int idx = r * 64 + lane;
        float v = user_w[idx];
        float ss = v * v;
        #pragma unroll
        for (int m = 32; m >= 1; m >>= 1) ss += __shfl_xor(ss, m, 64);
        float inv = dis[r] / fmaxf(sqrtf(ss), 1e-12f);
        float o = v * inv;
        y0[idx] = o;
        if (use_acc) acc[idx] = o;
    }
}

// ---------------- initial features: items y0 = dis * l2norm(proj) ----------------
__global__ void __launch_bounds__(256, 1)
k_items(const float* __restrict__ audio, const float* __restrict__ art,
        const float* __restrict__ alb, const int* __restrict__ aid,
        const int* __restrict__ alid, const float* __restrict__ Wp,
        const float* __restrict__ bp, const float* __restrict__ dis,
        float* __restrict__ y0item, float* __restrict__ accitem, int use_acc) {
    int lane = threadIdx.x & 63;
    float wreg[128];                     // lane d holds column d of Wp [128x64]
    #pragma unroll
    for (int k = 0; k < 128; ++k) wreg[k] = Wp[k * 64 + lane];
    float bias = bp[lane];
    int wv = (blockIdx.x * blockDim.x + threadIdx.x) >> 6;
    int nw = (gridDim.x * blockDim.x) >> 6;
    for (int i = wv; i < I_CNT; i += nw) {
        float vlow = audio[i * 64 + lane];   // AUDIO_SCALE=1
        int a_ = aid[i], al_ = alid[i];
        float vhigh = art[a_ * 64 + lane] + alb[al_ * 64 + lane];  // META_SCALE=1
        float a0 = bias, a1 = 0.f, a2 = 0.f, a3 = 0.f;
        #pragma unroll
        for (int k = 0; k < 64; k += 4) {
            a0 = fmaf(__shfl(vlow, k + 0, 64), wreg[k + 0], a0);
            a1 = fmaf(__shfl(vlow, k + 1, 64), wreg[k + 1], a1);
            a2 = fmaf(__shfl(vlow, k + 2, 64), wreg[k + 2], a2);
            a3 = fmaf(__shfl(vlow, k + 3, 64), wreg[k + 3], a3);
        }
        #pragma unroll
        for (int k = 0; k < 64; k += 4) {
            a0 = fmaf(__shfl(vhigh, k + 0, 64), wreg[64 + k + 0], a0);
            a1 = fmaf(__shfl(vhigh, k + 1, 64), wreg[64 + k + 1], a1);
            a2 = fmaf(__shfl(vhigh, k + 2, 64), wreg[64 + k + 2], a2);
            a3 = fmaf(__shfl(vhigh, k + 3, 64), wreg[64 + k + 3], a3);
        }
        float o = (a0 + a1) + (a2 + a3);
        float ss = o * o;
        #pragma unroll
        for (int m = 32; m >= 1; m >>= 1) ss += __shfl_xor(ss, m, 64);
        o = o * (dis[U_CNT + i] / fmaxf(sqrtf(ss), 1e-12f));
        int idx = i * 64 + lane;
        y0item[idx] = o;
        if (use_acc) accitem[idx] = o;
    }
}

// ---------------- one LGConv round in y-space: y' = dis^2*(sum w*y[row] + y[c]) ----------------
__global__ void k_prop(const int* __restrict__ offs, const int2* __restrict__ csr,
                       const float* __restrict__ dis,
                       const float* __restrict__ yin, float* __restrict__ yout,
                       float* __restrict__ acc, int use_acc) {
    int lane = threadIdx.x & 63;
    int c = (blockIdx.x * 256 + threadIdx.x) >> 6;   // wave per node
    if (c >= N_CNT) return;
    int e = offs[c], end = offs[c + 1];
    float dc = dis[c];
    float s0 = 0.f, s1 = 0.f, s2 = 0.f, s3 = 0.f;
    for (; e + 3 < end; e += 4) {
        int2 e0 = csr[e], e1 = csr[e + 1], e2 = csr[e + 2], e3 = csr[e + 3];
        float x0v = yin[e0.x * 64 + lane];
        float x1v = yin[e1.x * 64 + lane];
        float x2v = yin[e2.x * 64 + lane];
        float x3v = yin[e3.x * 64 + lane];
        s0 = fmaf(__int_as_float(e0.y), x0v, s0);
        s1 = fmaf(__int_as_float(e1.y), x1v, s1);
        s2 = fmaf(__int_as_float(e2.y), x2v, s2);
        s3 = fmaf(__int_as_float(e3.y), x3v, s3);
    }
    for (; e < end; ++e) {
        int2 ee = csr[e];
        s0 = fmaf(__int_as_float(ee.y), yin[ee.x * 64 + lane], s0);
    }
    float sum = (s0 + s1) + (s2 + s3);
    int idx = c * 64 + lane;
    float res = (dc * dc) * (sum + yin[idx]);       // self loop folded, raw w in CSR
    yout[idx] = res;
    if (use_acc) acc[idx] += res;
}

// ---------------- epilogue A: l2norm(acc)  (scale-invariant: acc is y-sum) ----------------
__global__ void k_final_acc(const float* __restrict__ acc, float* __restrict__ out) {
    int lane = threadIdx.x & 63;
    int c = (blockIdx.x * 256 + threadIdx.x) >> 6;
    if (c >= N_CNT) return;
    int idx = c * 64 + lane;
    float v = acc[idx];
    float ss = v * v;
    #pragma unroll
    for (int m = 32; m >= 1; m >>= 1) ss += __shfl_xor(ss, m, 64);
    out[idx] = v / fmaxf(sqrtf(ss), 1e-12f);
}

// ---------------- epilogue B: l2norm(y0+y1+y2+y3), y3 lives in out ----------------
__global__ void k_final_sum(const float* __restrict__ y0, const float* __restrict__ y1,
                            const float* __restrict__ y2, float* __restrict__ out) {
    int lane = threadIdx.x & 63;
    int c = (blockIdx.x * 256 + threadIdx.x) >> 6;
    if (c >= N_CNT) return;
    int idx = c * 64 + lane;
    float v = y0[idx] + y1[idx] + y2[idx] + out[idx];
    float ss = v * v;
    #pragma unroll
    for (int m = 32; m >= 1; m >>= 1) ss += __shfl_xor(ss, m, 64);
    out[idx] = v / fmaxf(sqrtf(ss), 1e-12f);
}

extern "C" void kernel_launch(void* const* d_in, const int* in_sizes, int n_in,
                              void* d_out, int out_size, void* d_ws, size_t ws_size,
                              hipStream_t stream) {
    const int*   edge_src   = (const int*)  d_in[0];
    const int*   edge_dst   = (const int*)  d_in[1];
    const float* edge_attr  = (const float*)d_in[2];
    const float* user_w     = (const float*)d_in[3];
    const float* artist_w   = (const float*)d_in[4];
    const float* album_w    = (const float*)d_in[5];
    const float* item_audio = (const float*)d_in[6];
    const int*   artist_ids = (const int*)  d_in[7];
    const int*   album_ids  = (const int*)  d_in[8];
    const float* Wp         = (const float*)d_in[9];
    const float* bp         = (const float*)d_in[10];
    const float* W1         = (const float*)d_in[11];
    const float* b1         = (const float*)d_in[12];
    const float* W2         = (const float*)d_in[13];
    const float* b2         = (const float*)d_in[14];

    char* p = (char*)d_ws;
    auto carve = [&](size_t bytes) -> void* {
        void* q = (void*)p;
        p += (bytes + 255) & ~(size_t)255;
        return q;
    };
    // common carve (~28 MB)
    float* dis    = (float*)carve((size_t)N_CNT * 4);
    int2*  wr     = (int2*) carve((size_t)E_CNT * 8);       // {w, rank_s|rank_d<<16}
    int*   cnt    = (int*)  carve((size_t)N_CNT * 4);
    int*   offs   = (int*)  carve((size_t)(N_CNT + 1) * 4);
    int*   incl   = (int*)  carve((size_t)N_CNT * 4);
    int*   bsums  = (int*)  carve((size_t)NB_SCAN * 4);
    int*   bbase  = (int*)  carve((size_t)NB_SCAN * 4);
    int2*  csr    = (int2*) carve((size_t)2 * E_CNT * 8);
    const size_t XB = (size_t)N_CNT * 64 * 4;      // 76.8 MB per y buffer
    size_t used = (size_t)(p - (char*)d_ws);
    // Path B (no acc RMW) needs y0,y1,y2 in ws; y3 = d_out.
    int no_acc = (ws_size >= used + 3 * XB + (size_t)4096) ? 1 : 0;
    float *y0, *y1, *y2, *acc = nullptr;
    if (no_acc) {
        y0 = (float*)carve(XB);
        y1 = (float*)carve(XB);
        y2 = (float*)carve(XB);
    } else {
        y0 = (float*)carve(XB);        // ya
        acc = (float*)carve(XB);
        y1 = (float*)d_out;            // ping-pong via d_out (proven round 2/5)
        y2 = y0;
    }
    (void)in_sizes; (void)n_in; (void)out_size;

    hipMemsetAsync(cnt, 0, (size_t)N_CNT * 4, stream);
    k_edge_mlp<<<(E_CNT + 255) / 256, 256, 0, stream>>>(edge_src, edge_dst, edge_attr,
                                                        W1, b1, W2, b2, wr, cnt);
    k_scan1  <<<NB_SCAN, 256, 0, stream>>>(cnt, incl, bsums);
    k_scan2  <<<1, 256, 0, stream>>>(bsums, bbase, NB_SCAN);
    k_scan3  <<<NB_SCAN, 256, 0, stream>>>(incl, cnt, bbase, offs);
    k_scatter<<<(E_CNT + 255) / 256, 256, 0, stream>>>(edge_src, edge_dst, wr,
                                                       offs, csr);
    k_deg    <<<NB_SCAN, 256, 0, stream>>>(offs, csr, dis);
    k_users  <<<1024, 256, 0, stream>>>(user_w, dis, y0, acc, no_acc ? 0 : 1);
    k_items  <<<1024, 256, 0, stream>>>(item_audio, artist_w, album_w, artist_ids,
                                        album_ids, Wp, bp, dis,
                                        y0 + (size_t)U_CNT * 64,
                                        no_acc ? nullptr : acc + (size_t)U_CNT * 64,
                                        no_acc ? 0 : 1);
    if (no_acc) {
        float* y3 = (float*)d_out;
        k_prop<<<N_CNT / 4, 256, 0, stream>>>(offs, csr, dis, y0, y1, nullptr, 0);
        k_prop<<<N_CNT / 4, 256, 0, stream>>>(offs, csr, dis, y1, y2, nullptr, 0);
        k_prop<<<N_CNT / 4, 256, 0, stream>>>(offs, csr, dis, y2, y3, nullptr, 0);
        k_final_sum<<<N_CNT / 4, 256, 0, stream>>>(y0, y1, y2, (float*)d_out);
    } else {
        // y0 -> y1(d_out) -> y0 -> y1, accumulating into acc
        k_prop<<<N_CNT / 4, 256, 0, stream>>>(offs, csr, dis, y0, y1, acc, 1);
        k_prop<<<N_CNT / 4, 256, 0, stream>>>(offs, csr, dis, y1, y0, acc, 1);
        k_prop<<<N_CNT / 4, 256, 0, stream>>>(offs, csr, dis, y0, y1, acc, 1);
        k_final_acc<<<N_CNT / 4, 256, 0, stream>>>(acc, (float*)d_out);
    }
}

// Round 2
// 886.602 us; speedup vs baseline: 1.2389x; 1.0733x over previous
//
#include <hip/hip_runtime.h>
#include <hip/hip_bf16.h>

#define U_CNT 200000
#define I_CNT 100000
#define N_CNT 300000
#define E_CNT 1000000
#define ATTR_D 8
#define H_DIM 32
#define NB_SCAN ((N_CNT + 255) / 256)

// NOTE (rounds 1-4): all float inputs and the output are FLOAT32. absmax floor
// 1.95e-3 == bf16 rounding of the *reference*; threshold 1.26e-2.
// NOTE (round 5): k_edge_mlp was atomic-bound (4M atomics x 32B = 128MB WRITE).
// NOTE (round 6): deg via segment-sum post-scatter; dis[row] folded by k_rescale.
// NOTE (round 7): rank-capture scatter (no cursor atomics) + y-space reform
// (y = dis*x) killed k_rescale. 1098 -> 951 us, prediction matched.
// NOTE (round 8, this round): k_items was LDS-pipe latency-bound (12.8M
// ds_bpermute from 128 __shfl per item; VALUBusy 19%, occupancy 20% from
// wreg[128]). Rewritten as register-blocked LDS GEMM: 64x64 tile, thread =
// 4 items x 4 outs, per-k {1 float4 W read + 4 scalar X reads (pad 132,
// 2-way = free) + 16 fma}. Roofline: 1.64 GFLOP @ 157 TF ~ 11 us.

// ---------------- edge MLP + count histogram; rank capture ----------------
__global__ void k_edge_mlp(const int* __restrict__ src, const int* __restrict__ dst,
                           const float* __restrict__ attr,
                           const float* __restrict__ W1, const float* __restrict__ b1,
                           const float* __restrict__ W2, const float* __restrict__ b2,
                           int2* __restrict__ wr, int* __restrict__ cnt) {
    __shared__ float sW1[ATTR_D * H_DIM];
    __shared__ float sb1[H_DIM];
    __shared__ float sW2[H_DIM];
    __shared__ float sb2;
    int t = threadIdx.x;
    sW1[t] = W1[t];                      // blockDim==256==ATTR_D*H_DIM
    if (t < H_DIM) { sb1[t] = b1[t]; sW2[t] = W2[t]; }
    if (t == 0) sb2 = b2[0];
    __syncthreads();
    int e = blockIdx.x * 256 + t;
    if (e >= E_CNT) return;
    const float4* a4 = (const float4*)attr;     // 32B/row: two float4
    float4 r0 = a4[e * 2 + 0];
    float4 r1 = a4[e * 2 + 1];
    float a[8] = {r0.x, r0.y, r0.z, r0.w, r1.x, r1.y, r1.z, r1.w};
    float z = sb2;
    #pragma unroll
    for (int h = 0; h < H_DIM; ++h) {
        float acc = sb1[h];
        #pragma unroll
        for (int k = 0; k < 8; ++k) acc = fmaf(a[k], sW1[k * H_DIM + h], acc);
        acc = fmaxf(acc, 0.0f);
        z = fmaf(acc, sW2[h], z);
    }
    float w = 1.0f / (1.0f + __expf(-z));
    w = fmaxf(w, 1e-6f);
    int s = src[e], d = U_CNT + dst[e];
    int rs = atomicAdd(&cnt[s], 1);      // rank of e within node s's list
    int rd = atomicAdd(&cnt[d], 1);      // rank of e within node d's list
    wr[e] = make_int2(__float_as_int(w), rs | (rd << 16));   // deg << 65536
}

// ---------------- exclusive scan of cnt -> offs (3 kernels) ----------------
__global__ void k_scan1(const int* __restrict__ cnt, int* __restrict__ incl,
                        int* __restrict__ bsums) {
    __shared__ int s[256];
    int t = threadIdx.x;
    int i = blockIdx.x * 256 + t;
    int v = (i < N_CNT) ? cnt[i] : 0;
    s[t] = v;
    __syncthreads();
    #pragma unroll
    for (int off = 1; off < 256; off <<= 1) {
        int x = (t >= off) ? s[t - off] : 0;
        __syncthreads();
        s[t] += x;
        __syncthreads();
    }
    if (i < N_CNT) incl[i] = s[t];
    if (t == 255) bsums[blockIdx.x] = s[255];
}

__global__ void k_scan2(const int* __restrict__ bsums, int* __restrict__ bbase, int nb) {
    __shared__ int s[256];
    __shared__ int carry_s;
    int t = threadIdx.x;
    if (t == 0) carry_s = 0;
    __syncthreads();
    for (int start = 0; start < nb; start += 256) {
        int i = start + t;
        int v = (i < nb) ? bsums[i] : 0;
        s[t] = v;
        __syncthreads();
        #pragma unroll
        for (int off = 1; off < 256; off <<= 1) {
            int x = (t >= off) ? s[t - off] : 0;
            __syncthreads();
            s[t] += x;
            __syncthreads();
        }
        int carry = carry_s;
        if (i < nb) bbase[i] = carry + s[t] - v;  // exclusive
        __syncthreads();
        if (t == 255) carry_s += s[255];
        __syncthreads();
    }
}

__global__ void k_scan3(const int* __restrict__ incl, const int* __restrict__ cnt,
                        const int* __restrict__ bbase, int* __restrict__ offs) {
    int i = blockIdx.x * 256 + threadIdx.x;
    if (i < N_CNT) offs[i] = bbase[blockIdx.x] + incl[i] - cnt[i];
    if (i == 0) offs[N_CNT] = 2 * E_CNT;
}

// ---------------- scatter edges into CSR at offs[node]+rank (no atomics) ----------------
__global__ void k_scatter(const int* __restrict__ src, const int* __restrict__ dst,
                          const int2* __restrict__ wr, const int* __restrict__ offs,
                          int2* __restrict__ csr) {
    int e = blockIdx.x * 256 + threadIdx.x;
    if (e >= E_CNT) return;
    int2 v = wr[e];
    unsigned rk = (unsigned)v.y;
    int s = src[e], d = U_CNT + dst[e];
    csr[offs[s] + (rk & 0xffffu)] = make_int2(d, v.x);   // row under s, partner d
    csr[offs[d] + (rk >> 16)]     = make_int2(s, v.x);   // row under d, partner s
}

// ---------------- deg via segment sum (no atomics), dis = rsqrt(1+sum) ----------------
__global__ void k_deg(const int* __restrict__ offs, const int2* __restrict__ csr,
                      float* __restrict__ dis) {
    int i = blockIdx.x * 256 + threadIdx.x;
    if (i >= N_CNT) return;
    int b = offs[i], e = offs[i + 1];
    float s = 1.0f;                      // self loop weight
    for (int k = b; k < e; ++k) s += __int_as_float(csr[k].y);
    dis[i] = rsqrtf(s);                  // s >= 1 always
}

// ---------------- initial features: users y0 = dis * l2norm(user_w) ----------------
__global__ void k_users(const float* __restrict__ user_w, const float* __restrict__ dis,
                        float* __restrict__ y0, float* __restrict__ acc, int use_acc) {
    int lane = threadIdx.x & 63;
    int wv = (blockIdx.x * blockDim.x + threadIdx.x) >> 6;
    int nw = (gridDim.x * blockDim.x) >> 6;
    for (int r = wv; r < U_CNT; r += nw) {
        int idx = r * 64 + lane;
        float v = user_w[idx];
        float ss = v * v;
        #pragma unroll
        for (int m = 32; m >= 1; m >>= 1) ss += __shfl_xor(ss, m, 64);
        float inv = dis[r] / fmaxf(sqrtf(ss), 1e-12f);
        float o = v * inv;
        y0[idx] = o;
        if (use_acc) acc[idx] = o;
    }
}

// ---------------- items: register-blocked LDS GEMM [64 items x 64 outs] ----------------
// thread (a = t>>4, b = t&15): items ig..ig+3 (ig = a*4), outs b*4..b*4+3.
// sX padded to 132 floats/row -> per-k scalar reads are 2-way (free);
// sW [k][d] natural -> float4 reads 2-way (free).
__global__ void __launch_bounds__(256, 2)
k_items(const float* __restrict__ audio, const float* __restrict__ art,
        const float* __restrict__ alb, const int* __restrict__ aid,
        const int* __restrict__ alid, const float* __restrict__ Wp,
        const float* __restrict__ bp, const float* __restrict__ dis,
        float* __restrict__ y0item, float* __restrict__ accitem, int use_acc) {
    __shared__ float sW[128 * 64];       // [k][d], 32 KB
    __shared__ float sX[64 * 132];       // [i][f], pad 132, 33 KB
    int t = threadIdx.x;
    int base = blockIdx.x * 64;
    // stage Wp (row-major [128][64] == desired layout)
    {
        const float4* wg = (const float4*)Wp;
        float4* ws = (float4*)sW;
        #pragma unroll
        for (int r = 0; r < 8; ++r) ws[r * 256 + t] = wg[r * 256 + t];
    }
    // stage audio rows -> sX[i][0..63] (16 KB contiguous, coalesced)
    {
        const float4* g = (const float4*)audio + (size_t)base * 16;
        #pragma unroll
        for (int r = 0; r < 4; ++r) {
            int idx = r * 256 + t;               // 0..1023 float4s
            int i = idx >> 4, fq = idx & 15;
            float4 v = make_float4(0.f, 0.f, 0.f, 0.f);
            if (base + i < I_CNT) v = g[idx];
            *(float4*)&sX[i * 132 + fq * 4] = v;
        }
    }
    // stage meta -> sX[i][64..127] (one wave row per item, coalesced gathers)
    {
        int lane = t & 63, wv = t >> 6;
        #pragma unroll
        for (int i = wv; i < 64; i += 4) {
            int it = base + i;
            float v = 0.f;
            if (it < I_CNT) {
                int a_ = aid[it], al_ = alid[it];
                v = art[a_ * 64 + lane] + alb[al_ * 64 + lane];
            }
            sX[i * 132 + 64 + lane] = v;
        }
    }
    __syncthreads();
    int b4 = (t & 15) * 4;
    int ig = (t >> 4) * 4;
    float4 bias = *(const float4*)&bp[b4];
    float4 c0 = bias, c1 = bias, c2 = bias, c3 = bias;
    const float* x0p = &sX[(ig + 0) * 132];
    const float* x1p = &sX[(ig + 1) * 132];
    const float* x2p = &sX[(ig + 2) * 132];
    const float* x3p = &sX[(ig + 3) * 132];
    const float* wp0 = &sW[b4];
    #pragma unroll 4
    for (int k = 0; k < 128; ++k) {
        float4 w4 = *(const float4*)&wp0[k * 64];
        float x0 = x0p[k], x1 = x1p[k], x2 = x2p[k], x3 = x3p[k];
        c0.x = fmaf(x0, w4.x, c0.x); c0.y = fmaf(x0, w4.y, c0.y);
        c0.z = fmaf(x0, w4.z, c0.z); c0.w = fmaf(x0, w4.w, c0.w);
        c1.x = fmaf(x1, w4.x, c1.x); c1.y = fmaf(x1, w4.y, c1.y);
        c1.z = fmaf(x1, w4.z, c1.z); c1.w = fmaf(x1, w4.w, c1.w);
        c2.x = fmaf(x2, w4.x, c2.x); c2.y = fmaf(x2, w4.y, c2.y);
        c2.z = fmaf(x2, w4.z, c2.z); c2.w = fmaf(x2, w4.w, c2.w);
        c3.x = fmaf(x3, w4.x, c3.x); c3.y = fmaf(x3, w4.y, c3.y);
        c3.z = fmaf(x3, w4.z, c3.z); c3.w = fmaf(x3, w4.w, c3.w);
    }
    // per-item sum of squares: reduce across the 16 lanes (b) owning this item
    float s0 = c0.x * c0.x + c0.y * c0.y + c0.z * c0.z + c0.w * c0.w;
    float s1 = c1.x * c1.x + c1.y * c1.y + c1.z * c1.z + c1.w * c1.w;
    float s2 = c2.x * c2.x + c2.y * c2.y + c2.z * c2.z + c2.w * c2.w;
    float s3 = c3.x * c3.x + c3.y * c3.y + c3.z * c3.z + c3.w * c3.w;
    #pragma unroll
    for (int m = 1; m <= 8; m <<= 1) {
        s0 += __shfl_xor(s0, m, 64);
        s1 += __shfl_xor(s1, m, 64);
        s2 += __shfl_xor(s2, m, 64);
        s3 += __shfl_xor(s3, m, 64);
    }
    int it0 = base + ig;
    float q0 = (it0 + 0 < I_CNT) ? dis[U_CNT + it0 + 0] / fmaxf(sqrtf(s0), 1e-12f) : 0.f;
    float q1 = (it0 + 1 < I_CNT) ? dis[U_CNT + it0 + 1] / fmaxf(sqrtf(s1), 1e-12f) : 0.f;
    float q2 = (it0 + 2 < I_CNT) ? dis[U_CNT + it0 + 2] / fmaxf(sqrtf(s2), 1e-12f) : 0.f;
    float q3 = (it0 + 3 < I_CNT) ? dis[U_CNT + it0 + 3] / fmaxf(sqrtf(s3), 1e-12f) : 0.f;
    c0.x *= q0; c0.y *= q0; c0.z *= q0; c0.w *= q0;
    c1.x *= q1; c1.y *= q1; c1.z *= q1; c1.w *= q1;
    c2.x *= q2; c2.y *= q2; c2.z *= q2; c2.w *= q2;
    c3.x *= q3; c3.y *= q3; c3.z *= q3; c3.w *= q3;
    if (it0 + 0 < I_CNT) {
        *(float4*)&y0item[(size_t)(it0 + 0) * 64 + b4] = c0;
        if (use_acc) *(float4*)&accitem[(size_t)(it0 + 0) * 64 + b4] = c0;
    }
    if (it0 + 1 < I_CNT) {
        *(float4*)&y0item[(size_t)(it0 + 1) * 64 + b4] = c1;
        if (use_acc) *(float4*)&accitem[(size_t)(it0 + 1) * 64 + b4] = c1;
    }
    if (it0 + 2 < I_CNT) {
        *(float4*)&y0item[(size_t)(it0 + 2) * 64 + b4] = c2;
        if (use_acc) *(float4*)&accitem[(size_t)(it0 + 2) * 64 + b4] = c2;
    }
    if (it0 + 3 < I_CNT) {
        *(float4*)&y0item[(size_t)(it0 + 3) * 64 + b4] = c3;
        if (use_acc) *(float4*)&accitem[(size_t)(it0 + 3) * 64 + b4] = c3;
    }
}

// ---------------- one LGConv round in y-space: y' = dis^2*(sum w*y[row] + y[c]) ----------------
__global__ void k_prop(const int* __restrict__ offs, const int2* __restrict__ csr,
                       const float* __restrict__ dis,
                       const float* __restrict__ yin, float* __restrict__ yout,
                       float* __restrict__ acc, int use_acc) {
    int lane = threadIdx.x & 63;
    int c = (blockIdx.x * 256 + threadIdx.x) >> 6;   // wave per node
    if (c >= N_CNT) return;
    int e = offs[c], end = offs[c + 1];
    float dc = dis[c];
    float s0 = 0.f, s1 = 0.f, s2 = 0.f, s3 = 0.f;
    for (; e + 3 < end; e += 4) {
        int2 e0 = csr[e], e1 = csr[e + 1], e2 = csr[e + 2], e3 = csr[e + 3];
        float x0v = yin[e0.x * 64 + lane];
        float x1v = yin[e1.x * 64 + lane];
        float x2v = yin[e2.x * 64 + lane];
        float x3v = yin[e3.x * 64 + lane];
        s0 = fmaf(__int_as_float(e0.y), x0v, s0);
        s1 = fmaf(__int_as_float(e1.y), x1v, s1);
        s2 = fmaf(__int_as_float(e2.y), x2v, s2);
        s3 = fmaf(__int_as_float(e3.y), x3v, s3);
    }
    for (; e < end; ++e) {
        int2 ee = csr[e];
        s0 = fmaf(__int_as_float(ee.y), yin[ee.x * 64 + lane], s0);
    }
    float sum = (s0 + s1) + (s2 + s3);
    int idx = c * 64 + lane;
    float res = (dc * dc) * (sum + yin[idx]);       // self loop folded, raw w in CSR
    yout[idx] = res;
    if (use_acc) acc[idx] += res;
}

// ---------------- epilogue A: l2norm(acc)  (scale-invariant: acc is y-sum) ----------------
__global__ void k_final_acc(const float* __restrict__ acc, float* __restrict__ out) {
    int lane = threadIdx.x & 63;
    int c = (blockIdx.x * 256 + threadIdx.x) >> 6;
    if (c >= N_CNT) return;
    int idx = c * 64 + lane;
    float v = acc[idx];
    float ss = v * v;
    #pragma unroll
    for (int m = 32; m >= 1; m >>= 1) ss += __shfl_xor(ss, m, 64);
    out[idx] = v / fmaxf(sqrtf(ss), 1e-12f);
}

// ---------------- epilogue B: l2norm(y0+y1+y2+y3), y3 lives in out ----------------
__global__ void k_final_sum(const float* __restrict__ y0, const float* __restrict__ y1,
                            const float* __restrict__ y2, float* __restrict__ out) {
    int lane = threadIdx.x & 63;
    int c = (blockIdx.x * 256 + threadIdx.x) >> 6;
    if (c >= N_CNT) return;
    int idx = c * 64 + lane;
    float v = y0[idx] + y1[idx] + y2[idx] + out[idx];
    float ss = v * v;
    #pragma unroll
    for (int m = 32; m >= 1; m >>= 1) ss += __shfl_xor(ss, m, 64);
    out[idx] = v / fmaxf(sqrtf(ss), 1e-12f);
}

extern "C" void kernel_launch(void* const* d_in, const int* in_sizes, int n_in,
                              void* d_out, int out_size, void* d_ws, size_t ws_size,
                              hipStream_t stream) {
    const int*   edge_src   = (const int*)  d_in[0];
    const int*   edge_dst   = (const int*)  d_in[1];
    const float* edge_attr  = (const float*)d_in[2];
    const float* user_w     = (const float*)d_in[3];
    const float* artist_w   = (const float*)d_in[4];
    const float* album_w    = (const float*)d_in[5];
    const float* item_audio = (const float*)d_in[6];
    const int*   artist_ids = (const int*)  d_in[7];
    const int*   album_ids  = (const int*)  d_in[8];
    const float* Wp         = (const float*)d_in[9];
    const float* bp         = (const float*)d_in[10];
    const float* W1         = (const float*)d_in[11];
    const float* b1         = (const float*)d_in[12];
    const float* W2         = (const float*)d_in[13];
    const float* b2         = (const float*)d_in[14];

    char* p = (char*)d_ws;
    auto carve = [&](size_t bytes) -> void* {
        void* q = (void*)p;
        p += (bytes + 255) & ~(size_t)255;
        return q;
    };
    // common carve (~28 MB)
    float* dis    = (float*)carve((size_t)N_CNT * 4);
    int2*  wr     = (int2*) carve((size_t)E_CNT * 8);       // {w, rank_s|rank_d<<16}
    int*   cnt    = (int*)  carve((size_t)N_CNT * 4);
    int*   offs   = (int*)  carve((size_t)(N_CNT + 1) * 4);
    int*   incl   = (int*)  carve((size_t)N_CNT * 4);
    int*   bsums  = (int*)  carve((size_t)NB_SCAN * 4);
    int*   bbase  = (int*)  carve((size_t)NB_SCAN * 4);
    int2*  csr    = (int2*) carve((size_t)2 * E_CNT * 8);
    const size_t XB = (size_t)N_CNT * 64 * 4;      // 76.8 MB per y buffer
    size_t used = (size_t)(p - (char*)d_ws);
    // Path B (no acc RMW) needs y0,y1,y2 in ws; y3 = d_out.
    int no_acc = (ws_size >= used + 3 * XB + (size_t)4096) ? 1 : 0;
    float *y0, *y1, *y2, *acc = nullptr;
    if (no_acc) {
        y0 = (float*)carve(XB);
        y1 = (float*)carve(XB);
        y2 = (float*)carve(XB);
    } else {
        y0 = (float*)carve(XB);        // ya
        acc = (float*)carve(XB);
        y1 = (float*)d_out;            // ping-pong via d_out (proven round 2/5)
        y2 = y0;
    }
    (void)in_sizes; (void)n_in; (void)out_size;

    hipMemsetAsync(cnt, 0, (size_t)N_CNT * 4, stream);
    k_edge_mlp<<<(E_CNT + 255) / 256, 256, 0, stream>>>(edge_src, edge_dst, edge_attr,
                                                        W1, b1, W2, b2, wr, cnt);
    k_scan1  <<<NB_SCAN, 256, 0, stream>>>(cnt, incl, bsums);
    k_scan2  <<<1, 256, 0, stream>>>(bsums, bbase, NB_SCAN);
    k_scan3  <<<NB_SCAN, 256, 0, stream>>>(incl, cnt, bbase, offs);
    k_scatter<<<(E_CNT + 255) / 256, 256, 0, stream>>>(edge_src, edge_dst, wr,
                                                       offs, csr);
    k_deg    <<<NB_SCAN, 256, 0, stream>>>(offs, csr, dis);
    k_users  <<<1024, 256, 0, stream>>>(user_w, dis, y0, acc, no_acc ? 0 : 1);
    k_items  <<<(I_CNT + 63) / 64, 256, 0, stream>>>(item_audio, artist_w, album_w,
                                        artist_ids, album_ids, Wp, bp, dis,
                                        y0 + (size_t)U_CNT * 64,
                                        no_acc ? nullptr : acc + (size_t)U_CNT * 64,
                                        no_acc ? 0 : 1);
    if (no_acc) {
        float* y3 = (float*)d_out;
        k_prop<<<N_CNT / 4, 256, 0, stream>>>(offs, csr, dis, y0, y1, nullptr, 0);
        k_prop<<<N_CNT / 4, 256, 0, stream>>>(offs, csr, dis, y1, y2, nullptr, 0);
        k_prop<<<N_CNT / 4, 256, 0, stream>>>(offs, csr, dis, y2, y3, nullptr, 0);
        k_final_sum<<<N_CNT / 4, 256, 0, stream>>>(y0, y1, y2, (float*)d_out);
    } else {
        // y0 -> y1(d_out) -> y0 -> y1, accumulating into acc
        k_prop<<<N_CNT / 4, 256, 0, stream>>>(offs, csr, dis, y0, y1, acc, 1);
        k_prop<<<N_CNT / 4, 256, 0, stream>>>(offs, csr, dis, y1, y0, acc, 1);
        k_prop<<<N_CNT / 4, 256, 0, stream>>>(offs, csr, dis, y0, y1, acc, 1);
        k_final_acc<<<N_CNT / 4, 256, 0, stream>>>(acc, (float*)d_out);
    }
}

// Round 3
// 830.595 us; speedup vs baseline: 1.3225x; 1.0674x over previous
//
#include <hip/hip_runtime.h>
#include <hip/hip_bf16.h>

#define U_CNT 200000
#define I_CNT 100000
#define N_CNT 300000
#define E_CNT 1000000
#define ATTR_D 8
#define H_DIM 32
#define NB_SCAN ((N_CNT + 255) / 256)

// NOTE (rounds 1-4): all float inputs and the output are FLOAT32. absmax floor
// 1.95e-3 == bf16 rounding of the *reference*; threshold 1.26e-2.
// NOTE (round 5): k_edge_mlp was atomic-bound (4M atomics x 32B = 128MB WRITE).
// NOTE (round 6): deg via segment-sum post-scatter; dis[row] folded by k_rescale.
// NOTE (round 7): rank-capture scatter (no cursor atomics) + y-space reform
// (y = dis*x) killed k_rescale. 1098 -> 951 us, matched.
// NOTE (round 8): k_items rewritten as register-blocked LDS GEMM (was 12.8M
// ds_bpermute latency-bound). 951 -> 886 us, matched.
// NOTE (round 9, this round): k_prop FETCH=288.7MB vs ~95MB unique -> LLC
// thrash (4 fp32 y-buffers = 307MB > 256MB LLC). Store y in BF16 (fp32
// compute, RNE): gather rows 256B->128B, y-state 153.6MB fits LLC.
// Predicted absmax ~4-6e-3 (<< 1.26e-2 threshold).

typedef unsigned short ubf;

__device__ __forceinline__ float b2f(ubf b) {
    return __uint_as_float((unsigned)b << 16);
}
__device__ __forceinline__ ubf f2b(float v) {
    unsigned u = __float_as_uint(v);
    u += 0x7fffu + ((u >> 16) & 1u);           // round to nearest even
    return (ubf)(u >> 16);
}

// ---------------- edge MLP + count histogram; rank capture ----------------
__global__ void k_edge_mlp(const int* __restrict__ src, const int* __restrict__ dst,
                           const float* __restrict__ attr,
                           const float* __restrict__ W1, const float* __restrict__ b1,
                           const float* __restrict__ W2, const float* __restrict__ b2,
                           int2* __restrict__ wr, int* __restrict__ cnt) {
    __shared__ float sW1[ATTR_D * H_DIM];
    __shared__ float sb1[H_DIM];
    __shared__ float sW2[H_DIM];
    __shared__ float sb2;
    int t = threadIdx.x;
    sW1[t] = W1[t];                      // blockDim==256==ATTR_D*H_DIM
    if (t < H_DIM) { sb1[t] = b1[t]; sW2[t] = W2[t]; }
    if (t == 0) sb2 = b2[0];
    __syncthreads();
    int e = blockIdx.x * 256 + t;
    if (e >= E_CNT) return;
    const float4* a4 = (const float4*)attr;     // 32B/row: two float4
    float4 r0 = a4[e * 2 + 0];
    float4 r1 = a4[e * 2 + 1];
    float a[8] = {r0.x, r0.y, r0.z, r0.w, r1.x, r1.y, r1.z, r1.w};
    float z = sb2;
    #pragma unroll
    for (int h = 0; h < H_DIM; ++h) {
        float acc = sb1[h];
        #pragma unroll
        for (int k = 0; k < 8; ++k) acc = fmaf(a[k], sW1[k * H_DIM + h], acc);
        acc = fmaxf(acc, 0.0f);
        z = fmaf(acc, sW2[h], z);
    }
    float w = 1.0f / (1.0f + __expf(-z));
    w = fmaxf(w, 1e-6f);
    int s = src[e], d = U_CNT + dst[e];
    int rs = atomicAdd(&cnt[s], 1);      // rank of e within node s's list
    int rd = atomicAdd(&cnt[d], 1);      // rank of e within node d's list
    wr[e] = make_int2(__float_as_int(w), rs | (rd << 16));   // deg << 65536
}

// ---------------- exclusive scan of cnt -> offs (3 kernels) ----------------
__global__ void k_scan1(const int* __restrict__ cnt, int* __restrict__ incl,
                        int* __restrict__ bsums) {
    __shared__ int s[256];
    int t = threadIdx.x;
    int i = blockIdx.x * 256 + t;
    int v = (i < N_CNT) ? cnt[i] : 0;
    s[t] = v;
    __syncthreads();
    #pragma unroll
    for (int off = 1; off < 256; off <<= 1) {
        int x = (t >= off) ? s[t - off] : 0;
        __syncthreads();
        s[t] += x;
        __syncthreads();
    }
    if (i < N_CNT) incl[i] = s[t];
    if (t == 255) bsums[blockIdx.x] = s[255];
}

__global__ void k_scan2(const int* __restrict__ bsums, int* __restrict__ bbase, int nb) {
    __shared__ int s[256];
    __shared__ int carry_s;
    int t = threadIdx.x;
    if (t == 0) carry_s = 0;
    __syncthreads();
    for (int start = 0; start < nb; start += 256) {
        int i = start + t;
        int v = (i < nb) ? bsums[i] : 0;
        s[t] = v;
        __syncthreads();
        #pragma unroll
        for (int off = 1; off < 256; off <<= 1) {
            int x = (t >= off) ? s[t - off] : 0;
            __syncthreads();
            s[t] += x;
            __syncthreads();
        }
        int carry = carry_s;
        if (i < nb) bbase[i] = carry + s[t] - v;  // exclusive
        __syncthreads();
        if (t == 255) carry_s += s[255];
        __syncthreads();
    }
}

__global__ void k_scan3(const int* __restrict__ incl, const int* __restrict__ cnt,
                        const int* __restrict__ bbase, int* __restrict__ offs) {
    int i = blockIdx.x * 256 + threadIdx.x;
    if (i < N_CNT) offs[i] = bbase[blockIdx.x] + incl[i] - cnt[i];
    if (i == 0) offs[N_CNT] = 2 * E_CNT;
}

// ---------------- scatter edges into CSR at offs[node]+rank (no atomics) ----------------
__global__ void k_scatter(const int* __restrict__ src, const int* __restrict__ dst,
                          const int2* __restrict__ wr, const int* __restrict__ offs,
                          int2* __restrict__ csr) {
    int e = blockIdx.x * 256 + threadIdx.x;
    if (e >= E_CNT) return;
    int2 v = wr[e];
    unsigned rk = (unsigned)v.y;
    int s = src[e], d = U_CNT + dst[e];
    csr[offs[s] + (rk & 0xffffu)] = make_int2(d, v.x);   // row under s, partner d
    csr[offs[d] + (rk >> 16)]     = make_int2(s, v.x);   // row under d, partner s
}

// ---------------- deg via segment sum (no atomics), dis = rsqrt(1+sum) ----------------
__global__ void k_deg(const int* __restrict__ offs, const int2* __restrict__ csr,
                      float* __restrict__ dis) {
    int i = blockIdx.x * 256 + threadIdx.x;
    if (i >= N_CNT) return;
    int b = offs[i], e = offs[i + 1];
    float s = 1.0f;                      // self loop weight
    for (int k = b; k < e; ++k) s += __int_as_float(csr[k].y);
    dis[i] = rsqrtf(s);                  // s >= 1 always
}

// ---------------- initial features: users y0 = dis * l2norm(user_w) ----------------
__global__ void k_users(const float* __restrict__ user_w, const float* __restrict__ dis,
                        ubf* __restrict__ y0, float* __restrict__ acc, int use_acc) {
    int lane = threadIdx.x & 63;
    int wv = (blockIdx.x * blockDim.x + threadIdx.x) >> 6;
    int nw = (gridDim.x * blockDim.x) >> 6;
    for (int r = wv; r < U_CNT; r += nw) {
        int idx = r * 64 + lane;
        float v = user_w[idx];
        float ss = v * v;
        #pragma unroll
        for (int m = 32; m >= 1; m >>= 1) ss += __shfl_xor(ss, m, 64);
        float inv = dis[r] / fmaxf(sqrtf(ss), 1e-12f);
        float o = v * inv;
        y0[idx] = f2b(o);
        if (use_acc) acc[idx] = o;
    }
}

// ---------------- items: register-blocked LDS GEMM [64 items x 64 outs] ----------------
__global__ void __launch_bounds__(256, 2)
k_items(const float* __restrict__ audio, const float* __restrict__ art,
        const float* __restrict__ alb, const int* __restrict__ aid,
        const int* __restrict__ alid, const float* __restrict__ Wp,
        const float* __restrict__ bp, const float* __restrict__ dis,
        ubf* __restrict__ y0item, float* __restrict__ accitem, int use_acc) {
    __shared__ float sW[128 * 64];       // [k][d], 32 KB
    __shared__ float sX[64 * 132];       // [i][f], pad 132, 33 KB
    int t = threadIdx.x;
    int base = blockIdx.x * 64;
    // stage Wp (row-major [128][64] == desired layout)
    {
        const float4* wg = (const float4*)Wp;
        float4* ws = (float4*)sW;
        #pragma unroll
        for (int r = 0; r < 8; ++r) ws[r * 256 + t] = wg[r * 256 + t];
    }
    // stage audio rows -> sX[i][0..63]
    {
        const float4* g = (const float4*)audio + (size_t)base * 16;
        #pragma unroll
        for (int r = 0; r < 4; ++r) {
            int idx = r * 256 + t;               // 0..1023 float4s
            int i = idx >> 4, fq = idx & 15;
            float4 v = make_float4(0.f, 0.f, 0.f, 0.f);
            if (base + i < I_CNT) v = g[idx];
            *(float4*)&sX[i * 132 + fq * 4] = v;
        }
    }
    // stage meta -> sX[i][64..127]
    {
        int lane = t & 63, wv = t >> 6;
        #pragma unroll
        for (int i = wv; i < 64; i += 4) {
            int it = base + i;
            float v = 0.f;
            if (it < I_CNT) {
                int a_ = aid[it], al_ = alid[it];
                v = art[a_ * 64 + lane] + alb[al_ * 64 + lane];
            }
            sX[i * 132 + 64 + lane] = v;
        }
    }
    __syncthreads();
    int b4 = (t & 15) * 4;
    int ig = (t >> 4) * 4;
    float4 bias = *(const float4*)&bp[b4];
    float4 c0 = bias, c1 = bias, c2 = bias, c3 = bias;
    const float* x0p = &sX[(ig + 0) * 132];
    const float* x1p = &sX[(ig + 1) * 132];
    const float* x2p = &sX[(ig + 2) * 132];
    const float* x3p = &sX[(ig + 3) * 132];
    const float* wp0 = &sW[b4];
    #pragma unroll 4
    for (int k = 0; k < 128; ++k) {
        float4 w4 = *(const float4*)&wp0[k * 64];
        float x0 = x0p[k], x1 = x1p[k], x2 = x2p[k], x3 = x3p[k];
        c0.x = fmaf(x0, w4.x, c0.x); c0.y = fmaf(x0, w4.y, c0.y);
        c0.z = fmaf(x0, w4.z, c0.z); c0.w = fmaf(x0, w4.w, c0.w);
        c1.x = fmaf(x1, w4.x, c1.x); c1.y = fmaf(x1, w4.y, c1.y);
        c1.z = fmaf(x1, w4.z, c1.z); c1.w = fmaf(x1, w4.w, c1.w);
        c2.x = fmaf(x2, w4.x, c2.x); c2.y = fmaf(x2, w4.y, c2.y);
        c2.z = fmaf(x2, w4.z, c2.z); c2.w = fmaf(x2, w4.w, c2.w);
        c3.x = fmaf(x3, w4.x, c3.x); c3.y = fmaf(x3, w4.y, c3.y);
        c3.z = fmaf(x3, w4.z, c3.z); c3.w = fmaf(x3, w4.w, c3.w);
    }
    // per-item sum of squares across the 16 lanes owning this item
    float s0 = c0.x * c0.x + c0.y * c0.y + c0.z * c0.z + c0.w * c0.w;
    float s1 = c1.x * c1.x + c1.y * c1.y + c1.z * c1.z + c1.w * c1.w;
    float s2 = c2.x * c2.x + c2.y * c2.y + c2.z * c2.z + c2.w * c2.w;
    float s3 = c3.x * c3.x + c3.y * c3.y + c3.z * c3.z + c3.w * c3.w;
    #pragma unroll
    for (int m = 1; m <= 8; m <<= 1) {
        s0 += __shfl_xor(s0, m, 64);
        s1 += __shfl_xor(s1, m, 64);
        s2 += __shfl_xor(s2, m, 64);
        s3 += __shfl_xor(s3, m, 64);
    }
    int it0 = base + ig;
    float q0 = (it0 + 0 < I_CNT) ? dis[U_CNT + it0 + 0] / fmaxf(sqrtf(s0), 1e-12f) : 0.f;
    float q1 = (it0 + 1 < I_CNT) ? dis[U_CNT + it0 + 1] / fmaxf(sqrtf(s1), 1e-12f) : 0.f;
    float q2 = (it0 + 2 < I_CNT) ? dis[U_CNT + it0 + 2] / fmaxf(sqrtf(s2), 1e-12f) : 0.f;
    float q3 = (it0 + 3 < I_CNT) ? dis[U_CNT + it0 + 3] / fmaxf(sqrtf(s3), 1e-12f) : 0.f;
    c0.x *= q0; c0.y *= q0; c0.z *= q0; c0.w *= q0;
    c1.x *= q1; c1.y *= q1; c1.z *= q1; c1.w *= q1;
    c2.x *= q2; c2.y *= q2; c2.z *= q2; c2.w *= q2;
    c3.x *= q3; c3.y *= q3; c3.z *= q3; c3.w *= q3;
    if (it0 + 0 < I_CNT) {
        ushort4 o = make_ushort4(f2b(c0.x), f2b(c0.y), f2b(c0.z), f2b(c0.w));
        *(ushort4*)&y0item[(size_t)(it0 + 0) * 64 + b4] = o;
        if (use_acc) *(float4*)&accitem[(size_t)(it0 + 0) * 64 + b4] = c0;
    }
    if (it0 + 1 < I_CNT) {
        ushort4 o = make_ushort4(f2b(c1.x), f2b(c1.y), f2b(c1.z), f2b(c1.w));
        *(ushort4*)&y0item[(size_t)(it0 + 1) * 64 + b4] = o;
        if (use_acc) *(float4*)&accitem[(size_t)(it0 + 1) * 64 + b4] = c1;
    }
    if (it0 + 2 < I_CNT) {
        ushort4 o = make_ushort4(f2b(c2.x), f2b(c2.y), f2b(c2.z), f2b(c2.w));
        *(ushort4*)&y0item[(size_t)(it0 + 2) * 64 + b4] = o;
        if (use_acc) *(float4*)&accitem[(size_t)(it0 + 2) * 64 + b4] = c2;
    }
    if (it0 + 3 < I_CNT) {
        ushort4 o = make_ushort4(f2b(c3.x), f2b(c3.y), f2b(c3.z), f2b(c3.w));
        *(ushort4*)&y0item[(size_t)(it0 + 3) * 64 + b4] = o;
        if (use_acc) *(float4*)&accitem[(size_t)(it0 + 3) * 64 + b4] = c3;
    }
}

// ---------------- one LGConv round in y-space (bf16 storage, fp32 math) ----------------
__global__ void k_prop(const int* __restrict__ offs, const int2* __restrict__ csr,
                       const float* __restrict__ dis,
                       const ubf* __restrict__ yin, ubf* __restrict__ yout,
                       float* __restrict__ acc, int use_acc) {
    int lane = threadIdx.x & 63;
    int c = (blockIdx.x * 256 + threadIdx.x) >> 6;   // wave per node
    if (c >= N_CNT) return;
    int e = offs[c], end = offs[c + 1];
    float dc = dis[c];
    float s0 = 0.f, s1 = 0.f, s2 = 0.f, s3 = 0.f;
    for (; e + 3 < end; e += 4) {
        int2 e0 = csr[e], e1 = csr[e + 1], e2 = csr[e + 2], e3 = csr[e + 3];
        float x0v = b2f(yin[e0.x * 64 + lane]);
        float x1v = b2f(yin[e1.x * 64 + lane]);
        float x2v = b2f(yin[e2.x * 64 + lane]);
        float x3v = b2f(yin[e3.x * 64 + lane]);
        s0 = fmaf(__int_as_float(e0.y), x0v, s0);
        s1 = fmaf(__int_as_float(e1.y), x1v, s1);
        s2 = fmaf(__int_as_float(e2.y), x2v, s2);
        s3 = fmaf(__int_as_float(e3.y), x3v, s3);
    }
    for (; e < end; ++e) {
        int2 ee = csr[e];
        s0 = fmaf(__int_as_float(ee.y), b2f(yin[ee.x * 64 + lane]), s0);
    }
    float sum = (s0 + s1) + (s2 + s3);
    int idx = c * 64 + lane;
    float res = (dc * dc) * (sum + b2f(yin[idx]));  // self loop folded, raw w in CSR
    yout[idx] = f2b(res);
    if (use_acc) acc[idx] += res;
}

// ---------------- epilogue A: l2norm(acc)  (acc fp32, may alias out) ----------------
__global__ void k_final_acc(const float* __restrict__ acc, float* __restrict__ out) {
    int lane = threadIdx.x & 63;
    int c = (blockIdx.x * 256 + threadIdx.x) >> 6;
    if (c >= N_CNT) return;
    int idx = c * 64 + lane;
    float v = acc[idx];
    float ss = v * v;
    #pragma unroll
    for (int m = 32; m >= 1; m >>= 1) ss += __shfl_xor(ss, m, 64);
    out[idx] = v / fmaxf(sqrtf(ss), 1e-12f);
}

// ---------------- epilogue B: l2norm(y0+y1+y2+y3), all bf16 ----------------
__global__ void k_final_sum(const ubf* __restrict__ y0, const ubf* __restrict__ y1,
                            const ubf* __restrict__ y2, const ubf* __restrict__ y3,
                            float* __restrict__ out) {
    int lane = threadIdx.x & 63;
    int c = (blockIdx.x * 256 + threadIdx.x) >> 6;
    if (c >= N_CNT) return;
    int idx = c * 64 + lane;
    float v = b2f(y0[idx]) + b2f(y1[idx]) + b2f(y2[idx]) + b2f(y3[idx]);
    float ss = v * v;
    #pragma unroll
    for (int m = 32; m >= 1; m >>= 1) ss += __shfl_xor(ss, m, 64);
    out[idx] = v / fmaxf(sqrtf(ss), 1e-12f);
}

extern "C" void kernel_launch(void* const* d_in, const int* in_sizes, int n_in,
                              void* d_out, int out_size, void* d_ws, size_t ws_size,
                              hipStream_t stream) {
    const int*   edge_src   = (const int*)  d_in[0];
    const int*   edge_dst   = (const int*)  d_in[1];
    const float* edge_attr  = (const float*)d_in[2];
    const float* user_w     = (const float*)d_in[3];
    const float* artist_w   = (const float*)d_in[4];
    const float* album_w    = (const float*)d_in[5];
    const float* item_audio = (const float*)d_in[6];
    const int*   artist_ids = (const int*)  d_in[7];
    const int*   album_ids  = (const int*)  d_in[8];
    const float* Wp         = (const float*)d_in[9];
    const float* bp         = (const float*)d_in[10];
    const float* W1         = (const float*)d_in[11];
    const float* b1         = (const float*)d_in[12];
    const float* W2         = (const float*)d_in[13];
    const float* b2         = (const float*)d_in[14];

    char* p = (char*)d_ws;
    auto carve = [&](size_t bytes) -> void* {
        void* q = (void*)p;
        p += (bytes + 255) & ~(size_t)255;
        return q;
    };
    // common carve (~28 MB)
    float* dis    = (float*)carve((size_t)N_CNT * 4);
    int2*  wr     = (int2*) carve((size_t)E_CNT * 8);       // {w, rank_s|rank_d<<16}
    int*   cnt    = (int*)  carve((size_t)N_CNT * 4);
    int*   offs   = (int*)  carve((size_t)(N_CNT + 1) * 4);
    int*   incl   = (int*)  carve((size_t)N_CNT * 4);
    int*   bsums  = (int*)  carve((size_t)NB_SCAN * 4);
    int*   bbase  = (int*)  carve((size_t)NB_SCAN * 4);
    int2*  csr    = (int2*) carve((size_t)2 * E_CNT * 8);
    const size_t YB = (size_t)N_CNT * 64 * 2;      // 38.4 MB per bf16 y buffer
    size_t used = (size_t)(p - (char*)d_ws);
    // Path B (no acc RMW) needs y0..y3 bf16 in ws; else ping-pong + fp32 acc in d_out.
    int no_acc = (ws_size >= used + 4 * YB + (size_t)4096) ? 1 : 0;
    ubf *y0, *y1, *y2, *y3;
    float* acc = nullptr;
    if (no_acc) {
        y0 = (ubf*)carve(YB);
        y1 = (ubf*)carve(YB);
        y2 = (ubf*)carve(YB);
        y3 = (ubf*)carve(YB);
    } else {
        y0 = (ubf*)carve(YB);
        y1 = (ubf*)carve(YB);
        y2 = y0;
        y3 = y1;
        acc = (float*)d_out;           // fp32 accumulator lives in d_out
    }
    (void)in_sizes; (void)n_in; (void)out_size;

    hipMemsetAsync(cnt, 0, (size_t)N_CNT * 4, stream);
    k_edge_mlp<<<(E_CNT + 255) / 256, 256, 0, stream>>>(edge_src, edge_dst, edge_attr,
                                                        W1, b1, W2, b2, wr, cnt);
    k_scan1  <<<NB_SCAN, 256, 0, stream>>>(cnt, incl, bsums);
    k_scan2  <<<1, 256, 0, stream>>>(bsums, bbase, NB_SCAN);
    k_scan3  <<<NB_SCAN, 256, 0, stream>>>(incl, cnt, bbase, offs);
    k_scatter<<<(E_CNT + 255) / 256, 256, 0, stream>>>(edge_src, edge_dst, wr,
                                                       offs, csr);
    k_deg    <<<NB_SCAN, 256, 0, stream>>>(offs, csr, dis);
    k_users  <<<1024, 256, 0, stream>>>(user_w, dis, y0, acc, no_acc ? 0 : 1);
    k_items  <<<(I_CNT + 63) / 64, 256, 0, stream>>>(item_audio, artist_w, album_w,
                                        artist_ids, album_ids, Wp, bp, dis,
                                        y0 + (size_t)U_CNT * 64,
                                        no_acc ? nullptr : acc + (size_t)U_CNT * 64,
                                        no_acc ? 0 : 1);
    if (no_acc) {
        k_prop<<<N_CNT / 4, 256, 0, stream>>>(offs, csr, dis, y0, y1, nullptr, 0);
        k_prop<<<N_CNT / 4, 256, 0, stream>>>(offs, csr, dis, y1, y2, nullptr, 0);
        k_prop<<<N_CNT / 4, 256, 0, stream>>>(offs, csr, dis, y2, y3, nullptr, 0);
        k_final_sum<<<N_CNT / 4, 256, 0, stream>>>(y0, y1, y2, y3, (float*)d_out);
    } else {
        // y0 -> y1 -> y0 -> y1 (bf16), accumulating fp32 into acc (= d_out)
        k_prop<<<N_CNT / 4, 256, 0, stream>>>(offs, csr, dis, y0, y1, acc, 1);
        k_prop<<<N_CNT / 4, 256, 0, stream>>>(offs, csr, dis, y1, y0, acc, 1);
        k_prop<<<N_CNT / 4, 256, 0, stream>>>(offs, csr, dis, y0, y1, acc, 1);
        k_final_acc<<<N_CNT / 4, 256, 0, stream>>>(acc, (float*)d_out);
    }
}

// Round 4
// 633.969 us; speedup vs baseline: 1.7327x; 1.3102x over previous
//
#include <hip/hip_runtime.h>
#include <hip/hip_bf16.h>

#define U_CNT 200000
#define I_CNT 100000
#define N_CNT 300000
#define E_CNT 1000000
#define ATTR_D 8
#define H_DIM 32
#define NB_SCAN ((N_CNT + 255) / 256)

// NOTE (rounds 1-4): all float inputs and the output are FLOAT32. absmax floor
// 1.95e-3 == bf16 rounding of the *reference*; threshold 1.26e-2.
// NOTE (round 5): k_edge_mlp was atomic-bound (4M atomics x 32B = 128MB WRITE).
// NOTE (round 6): deg via segment-sum post-scatter; dis[row] folded by k_rescale.
// NOTE (round 7): rank-capture scatter (no cursor atomics) + y-space reform
// (y = dis*x) killed k_rescale. 1098 -> 951 us, matched.
// NOTE (round 8): k_items rewritten as register-blocked LDS GEMM (was 12.8M
// ds_bpermute latency-bound). 951 -> 886 us, matched.
// NOTE (round 9): bf16 y-storage halved k_prop traffic (FETCH 289->147MB)
// but time only -9% (141->128us) -> k_prop is LATENCY-bound, not BW-bound.
// NOTE (round 10, this round): k_prop restructured for 4x memory concurrency:
// 4 nodes/wave, 16 lanes/node, ushort4 (8B)/lane. One gather instruction now
// covers 4 rows; 75k waves instead of 300k. Traffic unchanged by design.

typedef unsigned short ubf;

__device__ __forceinline__ float b2f(ubf b) {
    return __uint_as_float((unsigned)b << 16);
}
__device__ __forceinline__ ubf f2b(float v) {
    unsigned u = __float_as_uint(v);
    u += 0x7fffu + ((u >> 16) & 1u);           // round to nearest even
    return (ubf)(u >> 16);
}
__device__ __forceinline__ float4 b4f(ushort4 u) {
    return make_float4(b2f(u.x), b2f(u.y), b2f(u.z), b2f(u.w));
}

// ---------------- edge MLP + count histogram; rank capture ----------------
__global__ void k_edge_mlp(const int* __restrict__ src, const int* __restrict__ dst,
                           const float* __restrict__ attr,
                           const float* __restrict__ W1, const float* __restrict__ b1,
                           const float* __restrict__ W2, const float* __restrict__ b2,
                           int2* __restrict__ wr, int* __restrict__ cnt) {
    __shared__ float sW1[ATTR_D * H_DIM];
    __shared__ float sb1[H_DIM];
    __shared__ float sW2[H_DIM];
    __shared__ float sb2;
    int t = threadIdx.x;
    sW1[t] = W1[t];                      // blockDim==256==ATTR_D*H_DIM
    if (t < H_DIM) { sb1[t] = b1[t]; sW2[t] = W2[t]; }
    if (t == 0) sb2 = b2[0];
    __syncthreads();
    int e = blockIdx.x * 256 + t;
    if (e >= E_CNT) return;
    const float4* a4 = (const float4*)attr;     // 32B/row: two float4
    float4 r0 = a4[e * 2 + 0];
    float4 r1 = a4[e * 2 + 1];
    float a[8] = {r0.x, r0.y, r0.z, r0.w, r1.x, r1.y, r1.z, r1.w};
    float z = sb2;
    #pragma unroll
    for (int h = 0; h < H_DIM; ++h) {
        float acc = sb1[h];
        #pragma unroll
        for (int k = 0; k < 8; ++k) acc = fmaf(a[k], sW1[k * H_DIM + h], acc);
        acc = fmaxf(acc, 0.0f);
        z = fmaf(acc, sW2[h], z);
    }
    float w = 1.0f / (1.0f + __expf(-z));
    w = fmaxf(w, 1e-6f);
    int s = src[e], d = U_CNT + dst[e];
    int rs = atomicAdd(&cnt[s], 1);      // rank of e within node s's list
    int rd = atomicAdd(&cnt[d], 1);      // rank of e within node d's list
    wr[e] = make_int2(__float_as_int(w), rs | (rd << 16));   // deg << 65536
}

// ---------------- exclusive scan of cnt -> offs (3 kernels) ----------------
__global__ void k_scan1(const int* __restrict__ cnt, int* __restrict__ incl,
                        int* __restrict__ bsums) {
    __shared__ int s[256];
    int t = threadIdx.x;
    int i = blockIdx.x * 256 + t;
    int v = (i < N_CNT) ? cnt[i] : 0;
    s[t] = v;
    __syncthreads();
    #pragma unroll
    for (int off = 1; off < 256; off <<= 1) {
        int x = (t >= off) ? s[t - off] : 0;
        __syncthreads();
        s[t] += x;
        __syncthreads();
    }
    if (i < N_CNT) incl[i] = s[t];
    if (t == 255) bsums[blockIdx.x] = s[255];
}

__global__ void k_scan2(const int* __restrict__ bsums, int* __restrict__ bbase, int nb) {
    __shared__ int s[256];
    __shared__ int carry_s;
    int t = threadIdx.x;
    if (t == 0) carry_s = 0;
    __syncthreads();
    for (int start = 0; start < nb; start += 256) {
        int i = start + t;
        int v = (i < nb) ? bsums[i] : 0;
        s[t] = v;
        __syncthreads();
        #pragma unroll
        for (int off = 1; off < 256; off <<= 1) {
            int x = (t >= off) ? s[t - off] : 0;
            __syncthreads();
            s[t] += x;
            __syncthreads();
        }
        int carry = carry_s;
        if (i < nb) bbase[i] = carry + s[t] - v;  // exclusive
        __syncthreads();
        if (t == 255) carry_s += s[255];
        __syncthreads();
    }
}

__global__ void k_scan3(const int* __restrict__ incl, const int* __restrict__ cnt,
                        const int* __restrict__ bbase, int* __restrict__ offs) {
    int i = blockIdx.x * 256 + threadIdx.x;
    if (i < N_CNT) offs[i] = bbase[blockIdx.x] + incl[i] - cnt[i];
    if (i == 0) offs[N_CNT] = 2 * E_CNT;
}

// ---------------- scatter edges into CSR at offs[node]+rank (no atomics) ----------------
__global__ void k_scatter(const int* __restrict__ src, const int* __restrict__ dst,
                          const int2* __restrict__ wr, const int* __restrict__ offs,
                          int2* __restrict__ csr) {
    int e = blockIdx.x * 256 + threadIdx.x;
    if (e >= E_CNT) return;
    int2 v = wr[e];
    unsigned rk = (unsigned)v.y;
    int s = src[e], d = U_CNT + dst[e];
    csr[offs[s] + (rk & 0xffffu)] = make_int2(d, v.x);   // row under s, partner d
    csr[offs[d] + (rk >> 16)]     = make_int2(s, v.x);   // row under d, partner s
}

// ---------------- deg via segment sum (no atomics), dis = rsqrt(1+sum) ----------------
__global__ void k_deg(const int* __restrict__ offs, const int2* __restrict__ csr,
                      float* __restrict__ dis) {
    int i = blockIdx.x * 256 + threadIdx.x;
    if (i >= N_CNT) return;
    int b = offs[i], e = offs[i + 1];
    float s = 1.0f;                      // self loop weight
    for (int k = b; k < e; ++k) s += __int_as_float(csr[k].y);
    dis[i] = rsqrtf(s);                  // s >= 1 always
}

// ---------------- initial features: users y0 = dis * l2norm(user_w) ----------------
__global__ void k_users(const float* __restrict__ user_w, const float* __restrict__ dis,
                        ubf* __restrict__ y0, float* __restrict__ acc, int use_acc) {
    int lane = threadIdx.x & 63;
    int wv = (blockIdx.x * blockDim.x + threadIdx.x) >> 6;
    int nw = (gridDim.x * blockDim.x) >> 6;
    for (int r = wv; r < U_CNT; r += nw) {
        int idx = r * 64 + lane;
        float v = user_w[idx];
        float ss = v * v;
        #pragma unroll
        for (int m = 32; m >= 1; m >>= 1) ss += __shfl_xor(ss, m, 64);
        float inv = dis[r] / fmaxf(sqrtf(ss), 1e-12f);
        float o = v * inv;
        y0[idx] = f2b(o);
        if (use_acc) acc[idx] = o;
    }
}

// ---------------- items: register-blocked LDS GEMM [64 items x 64 outs] ----------------
__global__ void __launch_bounds__(256, 2)
k_items(const float* __restrict__ audio, const float* __restrict__ art,
        const float* __restrict__ alb, const int* __restrict__ aid,
        const int* __restrict__ alid, const float* __restrict__ Wp,
        const float* __restrict__ bp, const float* __restrict__ dis,
        ubf* __restrict__ y0item, float* __restrict__ accitem, int use_acc) {
    __shared__ float sW[128 * 64];       // [k][d], 32 KB
    __shared__ float sX[64 * 132];       // [i][f], pad 132, 33 KB
    int t = threadIdx.x;
    int base = blockIdx.x * 64;
    // stage Wp (row-major [128][64] == desired layout)
    {
        const float4* wg = (const float4*)Wp;
        float4* ws = (float4*)sW;
        #pragma unroll
        for (int r = 0; r < 8; ++r) ws[r * 256 + t] = wg[r * 256 + t];
    }
    // stage audio rows -> sX[i][0..63]
    {
        const float4* g = (const float4*)audio + (size_t)base * 16;
        #pragma unroll
        for (int r = 0; r < 4; ++r) {
            int idx = r * 256 + t;               // 0..1023 float4s
            int i = idx >> 4, fq = idx & 15;
            float4 v = make_float4(0.f, 0.f, 0.f, 0.f);
            if (base + i < I_CNT) v = g[idx];
            *(float4*)&sX[i * 132 + fq * 4] = v;
        }
    }
    // stage meta -> sX[i][64..127]
    {
        int lane = t & 63, wv = t >> 6;
        #pragma unroll
        for (int i = wv; i < 64; i += 4) {
            int it = base + i;
            float v = 0.f;
            if (it < I_CNT) {
                int a_ = aid[it], al_ = alid[it];
                v = art[a_ * 64 + lane] + alb[al_ * 64 + lane];
            }
            sX[i * 132 + 64 + lane] = v;
        }
    }
    __syncthreads();
    int b4 = (t & 15) * 4;
    int ig = (t >> 4) * 4;
    float4 bias = *(const float4*)&bp[b4];
    float4 c0 = bias, c1 = bias, c2 = bias, c3 = bias;
    const float* x0p = &sX[(ig + 0) * 132];
    const float* x1p = &sX[(ig + 1) * 132];
    const float* x2p = &sX[(ig + 2) * 132];
    const float* x3p = &sX[(ig + 3) * 132];
    const float* wp0 = &sW[b4];
    #pragma unroll 4
    for (int k = 0; k < 128; ++k) {
        float4 w4 = *(const float4*)&wp0[k * 64];
        float x0 = x0p[k], x1 = x1p[k], x2 = x2p[k], x3 = x3p[k];
        c0.x = fmaf(x0, w4.x, c0.x); c0.y = fmaf(x0, w4.y, c0.y);
        c0.z = fmaf(x0, w4.z, c0.z); c0.w = fmaf(x0, w4.w, c0.w);
        c1.x = fmaf(x1, w4.x, c1.x); c1.y = fmaf(x1, w4.y, c1.y);
        c1.z = fmaf(x1, w4.z, c1.z); c1.w = fmaf(x1, w4.w, c1.w);
        c2.x = fmaf(x2, w4.x, c2.x); c2.y = fmaf(x2, w4.y, c2.y);
        c2.z = fmaf(x2, w4.z, c2.z); c2.w = fmaf(x2, w4.w, c2.w);
        c3.x = fmaf(x3, w4.x, c3.x); c3.y = fmaf(x3, w4.y, c3.y);
        c3.z = fmaf(x3, w4.z, c3.z); c3.w = fmaf(x3, w4.w, c3.w);
    }
    // per-item sum of squares across the 16 lanes owning this item
    float s0 = c0.x * c0.x + c0.y * c0.y + c0.z * c0.z + c0.w * c0.w;
    float s1 = c1.x * c1.x + c1.y * c1.y + c1.z * c1.z + c1.w * c1.w;
    float s2 = c2.x * c2.x + c2.y * c2.y + c2.z * c2.z + c2.w * c2.w;
    float s3 = c3.x * c3.x + c3.y * c3.y + c3.z * c3.z + c3.w * c3.w;
    #pragma unroll
    for (int m = 1; m <= 8; m <<= 1) {
        s0 += __shfl_xor(s0, m, 64);
        s1 += __shfl_xor(s1, m, 64);
        s2 += __shfl_xor(s2, m, 64);
        s3 += __shfl_xor(s3, m, 64);
    }
    int it0 = base + ig;
    float q0 = (it0 + 0 < I_CNT) ? dis[U_CNT + it0 + 0] / fmaxf(sqrtf(s0), 1e-12f) : 0.f;
    float q1 = (it0 + 1 < I_CNT) ? dis[U_CNT + it0 + 1] / fmaxf(sqrtf(s1), 1e-12f) : 0.f;
    float q2 = (it0 + 2 < I_CNT) ? dis[U_CNT + it0 + 2] / fmaxf(sqrtf(s2), 1e-12f) : 0.f;
    float q3 = (it0 + 3 < I_CNT) ? dis[U_CNT + it0 + 3] / fmaxf(sqrtf(s3), 1e-12f) : 0.f;
    c0.x *= q0; c0.y *= q0; c0.z *= q0; c0.w *= q0;
    c1.x *= q1; c1.y *= q1; c1.z *= q1; c1.w *= q1;
    c2.x *= q2; c2.y *= q2; c2.z *= q2; c2.w *= q2;
    c3.x *= q3; c3.y *= q3; c3.z *= q3; c3.w *= q3;
    if (it0 + 0 < I_CNT) {
        ushort4 o = make_ushort4(f2b(c0.x), f2b(c0.y), f2b(c0.z), f2b(c0.w));
        *(ushort4*)&y0item[(size_t)(it0 + 0) * 64 + b4] = o;
        if (use_acc) *(float4*)&accitem[(size_t)(it0 + 0) * 64 + b4] = c0;
    }
    if (it0 + 1 < I_CNT) {
        ushort4 o = make_ushort4(f2b(c1.x), f2b(c1.y), f2b(c1.z), f2b(c1.w));
        *(ushort4*)&y0item[(size_t)(it0 + 1) * 64 + b4] = o;
        if (use_acc) *(float4*)&accitem[(size_t)(it0 + 1) * 64 + b4] = c1;
    }
    if (it0 + 2 < I_CNT) {
        ushort4 o = make_ushort4(f2b(c2.x), f2b(c2.y), f2b(c2.z), f2b(c2.w));
        *(ushort4*)&y0item[(size_t)(it0 + 2) * 64 + b4] = o;
        if (use_acc) *(float4*)&accitem[(size_t)(it0 + 2) * 64 + b4] = c2;
    }
    if (it0 + 3 < I_CNT) {
        ushort4 o = make_ushort4(f2b(c3.x), f2b(c3.y), f2b(c3.z), f2b(c3.w));
        *(ushort4*)&y0item[(size_t)(it0 + 3) * 64 + b4] = o;
        if (use_acc) *(float4*)&accitem[(size_t)(it0 + 3) * 64 + b4] = c3;
    }
}

// ---------------- LGConv round: 4 nodes/wave, 16 lanes/node, ushort4/lane ----------------
// y' = dis^2 * (sum w*y[partner] + y[c]); 4x memory concurrency vs wave/node.
__global__ void k_prop(const int* __restrict__ offs, const int2* __restrict__ csr,
                       const float* __restrict__ dis,
                       const ubf* __restrict__ yin, ubf* __restrict__ yout,
                       float* __restrict__ acc, int use_acc) {
    int lane = threadIdx.x & 63;
    int g = lane >> 4;                   // node group 0..3
    int s4 = (lane & 15) * 4;            // dims s4..s4+3
    int wv = (blockIdx.x * 256 + threadIdx.x) >> 6;
    int c = wv * 4 + g;                  // N_CNT % 4 == 0, grid sized exactly
    if (c >= N_CNT) return;
    int e = offs[c], end = offs[c + 1];
    float dc = dis[c];
    float4 a0 = make_float4(0.f, 0.f, 0.f, 0.f);
    float4 a1 = a0, a2 = a0, a3 = a0;
    for (; e + 3 < end; e += 4) {
        int2 e0 = csr[e], e1 = csr[e + 1], e2 = csr[e + 2], e3 = csr[e + 3];
        ushort4 g0 = *(const ushort4*)&yin[(size_t)e0.x * 64 + s4];
        ushort4 g1 = *(const ushort4*)&yin[(size_t)e1.x * 64 + s4];
        ushort4 g2 = *(const ushort4*)&yin[(size_t)e2.x * 64 + s4];
        ushort4 g3 = *(const ushort4*)&yin[(size_t)e3.x * 64 + s4];
        float w0 = __int_as_float(e0.y), w1 = __int_as_float(e1.y);
        float w2 = __int_as_float(e2.y), w3 = __int_as_float(e3.y);
        float4 f0 = b4f(g0), f1 = b4f(g1), f2 = b4f(g2), f3 = b4f(g3);
        a0.x = fmaf(w0, f0.x, a0.x); a0.y = fmaf(w0, f0.y, a0.y);
        a0.z = fmaf(w0, f0.z, a0.z); a0.w = fmaf(w0, f0.w, a0.w);
        a1.x = fmaf(w1, f1.x, a1.x); a1.y = fmaf(w1, f1.y, a1.y);
        a1.z = fmaf(w1, f1.z, a1.z); a1.w = fmaf(w1, f1.w, a1.w);
        a2.x = fmaf(w2, f2.x, a2.x); a2.y = fmaf(w2, f2.y, a2.y);
        a2.z = fmaf(w2, f2.z, a2.z); a2.w = fmaf(w2, f2.w, a2.w);
        a3.x = fmaf(w3, f3.x, a3.x); a3.y = fmaf(w3, f3.y, a3.y);
        a3.z = fmaf(w3, f3.z, a3.z); a3.w = fmaf(w3, f3.w, a3.w);
    }
    for (; e < end; ++e) {
        int2 ee = csr[e];
        ushort4 gg = *(const ushort4*)&yin[(size_t)ee.x * 64 + s4];
        float ww = __int_as_float(ee.y);
        float4 ff = b4f(gg);
        a0.x = fmaf(ww, ff.x, a0.x); a0.y = fmaf(ww, ff.y, a0.y);
        a0.z = fmaf(ww, ff.z, a0.z); a0.w = fmaf(ww, ff.w, a0.w);
    }
    size_t idx = (size_t)c * 64 + s4;
    float4 self = b4f(*(const ushort4*)&yin[idx]);
    float dc2 = dc * dc;
    float4 r;
    r.x = dc2 * (((a0.x + a1.x) + (a2.x + a3.x)) + self.x);
    r.y = dc2 * (((a0.y + a1.y) + (a2.y + a3.y)) + self.y);
    r.z = dc2 * (((a0.z + a1.z) + (a2.z + a3.z)) + self.z);
    r.w = dc2 * (((a0.w + a1.w) + (a2.w + a3.w)) + self.w);
    *(ushort4*)&yout[idx] = make_ushort4(f2b(r.x), f2b(r.y), f2b(r.z), f2b(r.w));
    if (use_acc) {
        float4* ap = (float4*)&acc[idx];
        float4 av = *ap;
        av.x += r.x; av.y += r.y; av.z += r.z; av.w += r.w;
        *ap = av;
    }
}

// ---------------- epilogue A: l2norm(acc)  (acc fp32, may alias out) ----------------
__global__ void k_final_acc(const float* __restrict__ acc, float* __restrict__ out) {
    int lane = threadIdx.x & 63;
    int c = (blockIdx.x * 256 + threadIdx.x) >> 6;
    if (c >= N_CNT) return;
    int idx = c * 64 + lane;
    float v = acc[idx];
    float ss = v * v;
    #pragma unroll
    for (int m = 32; m >= 1; m >>= 1) ss += __shfl_xor(ss, m, 64);
    out[idx] = v / fmaxf(sqrtf(ss), 1e-12f);
}

// ---------------- epilogue B: l2norm(y0+y1+y2+y3), all bf16 ----------------
__global__ void k_final_sum(const ubf* __restrict__ y0, const ubf* __restrict__ y1,
                            const ubf* __restrict__ y2, const ubf* __restrict__ y3,
                            float* __restrict__ out) {
    int lane = threadIdx.x & 63;
    int c = (blockIdx.x * 256 + threadIdx.x) >> 6;
    if (c >= N_CNT) return;
    int idx = c * 64 + lane;
    float v = b2f(y0[idx]) + b2f(y1[idx]) + b2f(y2[idx]) + b2f(y3[idx]);
    float ss = v * v;
    #pragma unroll
    for (int m = 32; m >= 1; m >>= 1) ss += __shfl_xor(ss, m, 64);
    out[idx] = v / fmaxf(sqrtf(ss), 1e-12f);
}

extern "C" void kernel_launch(void* const* d_in, const int* in_sizes, int n_in,
                              void* d_out, int out_size, void* d_ws, size_t ws_size,
                              hipStream_t stream) {
    const int*   edge_src   = (const int*)  d_in[0];
    const int*   edge_dst   = (const int*)  d_in[1];
    const float* edge_attr  = (const float*)d_in[2];
    const float* user_w     = (const float*)d_in[3];
    const float* artist_w   = (const float*)d_in[4];
    const float* album_w    = (const float*)d_in[5];
    const float* item_audio = (const float*)d_in[6];
    const int*   artist_ids = (const int*)  d_in[7];
    const int*   album_ids  = (const int*)  d_in[8];
    const float* Wp         = (const float*)d_in[9];
    const float* bp         = (const float*)d_in[10];
    const float* W1         = (const float*)d_in[11];
    const float* b1         = (const float*)d_in[12];
    const float* W2         = (const float*)d_in[13];
    const float* b2         = (const float*)d_in[14];

    char* p = (char*)d_ws;
    auto carve = [&](size_t bytes) -> void* {
        void* q = (void*)p;
        p += (bytes + 255) & ~(size_t)255;
        return q;
    };
    // common carve (~28 MB)
    float* dis    = (float*)carve((size_t)N_CNT * 4);
    int2*  wr     = (int2*) carve((size_t)E_CNT * 8);       // {w, rank_s|rank_d<<16}
    int*   cnt    = (int*)  carve((size_t)N_CNT * 4);
    int*   offs   = (int*)  carve((size_t)(N_CNT + 1) * 4);
    int*   incl   = (int*)  carve((size_t)N_CNT * 4);
    int*   bsums  = (int*)  carve((size_t)NB_SCAN * 4);
    int*   bbase  = (int*)  carve((size_t)NB_SCAN * 4);
    int2*  csr    = (int2*) carve((size_t)2 * E_CNT * 8);
    const size_t YB = (size_t)N_CNT * 64 * 2;      // 38.4 MB per bf16 y buffer
    size_t used = (size_t)(p - (char*)d_ws);
    // Path B (no acc RMW) needs y0..y3 bf16 in ws; else ping-pong + fp32 acc in d_out.
    int no_acc = (ws_size >= used + 4 * YB + (size_t)4096) ? 1 : 0;
    ubf *y0, *y1, *y2, *y3;
    float* acc = nullptr;
    if (no_acc) {
        y0 = (ubf*)carve(YB);
        y1 = (ubf*)carve(YB);
        y2 = (ubf*)carve(YB);
        y3 = (ubf*)carve(YB);
    } else {
        y0 = (ubf*)carve(YB);
        y1 = (ubf*)carve(YB);
        y2 = y0;
        y3 = y1;
        acc = (float*)d_out;           // fp32 accumulator lives in d_out
    }
    (void)in_sizes; (void)n_in; (void)out_size;

    hipMemsetAsync(cnt, 0, (size_t)N_CNT * 4, stream);
    k_edge_mlp<<<(E_CNT + 255) / 256, 256, 0, stream>>>(edge_src, edge_dst, edge_attr,
                                                        W1, b1, W2, b2, wr, cnt);
    k_scan1  <<<NB_SCAN, 256, 0, stream>>>(cnt, incl, bsums);
    k_scan2  <<<1, 256, 0, stream>>>(bsums, bbase, NB_SCAN);
    k_scan3  <<<NB_SCAN, 256, 0, stream>>>(incl, cnt, bbase, offs);
    k_scatter<<<(E_CNT + 255) / 256, 256, 0, stream>>>(edge_src, edge_dst, wr,
                                                       offs, csr);
    k_deg    <<<NB_SCAN, 256, 0, stream>>>(offs, csr, dis);
    k_users  <<<1024, 256, 0, stream>>>(user_w, dis, y0, acc, no_acc ? 0 : 1);
    k_items  <<<(I_CNT + 63) / 64, 256, 0, stream>>>(item_audio, artist_w, album_w,
                                        artist_ids, album_ids, Wp, bp, dis,
                                        y0 + (size_t)U_CNT * 64,
                                        no_acc ? nullptr : acc + (size_t)U_CNT * 64,
                                        no_acc ? 0 : 1);
    // 4 nodes per wave -> N/4 waves -> N/16 blocks of 256
    const int PROP_BLKS = N_CNT / 16;    // 18750
    if (no_acc) {
        k_prop<<<PROP_BLKS, 256, 0, stream>>>(offs, csr, dis, y0, y1, nullptr, 0);
        k_prop<<<PROP_BLKS, 256, 0, stream>>>(offs, csr, dis, y1, y2, nullptr, 0);
        k_prop<<<PROP_BLKS, 256, 0, stream>>>(offs, csr, dis, y2, y3, nullptr, 0);
        k_final_sum<<<N_CNT / 4, 256, 0, stream>>>(y0, y1, y2, y3, (float*)d_out);
    } else {
        // y0 -> y1 -> y0 -> y1 (bf16), accumulating fp32 into acc (= d_out)
        k_prop<<<PROP_BLKS, 256, 0, stream>>>(offs, csr, dis, y0, y1, acc, 1);
        k_prop<<<PROP_BLKS, 256, 0, stream>>>(offs, csr, dis, y1, y0, acc, 1);
        k_prop<<<PROP_BLKS, 256, 0, stream>>>(offs, csr, dis, y0, y1, acc, 1);
        k_final_acc<<<N_CNT / 4, 256, 0, stream>>>(acc, (float*)d_out);
    }
}